// Round 17
// baseline (787.573 us; speedup 1.0000x reference)
//
#include <hip/hip_runtime.h>
#include <math.h>

#define NB   32
#define C_   768
#define NQ   1024
#define NKV  256
#define NH_  12
#define HD_  64
#define FFC  3072
#define EPS_ 1e-5f

typedef __attribute__((ext_vector_type(8))) _Float16 f16x8;
typedef __attribute__((ext_vector_type(4))) _Float16 f16x4;
typedef __attribute__((ext_vector_type(2))) _Float16 f16x2;
typedef __attribute__((ext_vector_type(4))) float    f32x4;

__device__ __forceinline__ void gload_lds16(const void* g, void* l) {
  __builtin_amdgcn_global_load_lds((const __attribute__((address_space(1))) void*)g,
                                   (__attribute__((address_space(3))) void*)l, 16, 0, 0);
}

// gelu tanh-approx (sigmoid form), ~5 VALU ops vs ~30 for erff (R8 win).
__device__ __forceinline__ float gelu_f(float x) {
  return x / (1.f + __expf(-1.5957691216f * (x + 0.044715f * x * x * x)));
}

// ---------------- LayerNorm 1 (f16 out; only dw consumes it) ----------------
__global__ __launch_bounds__(256)
void ln_fwd_kernel(const float* __restrict__ x, const float* __restrict__ g,
                   const float* __restrict__ b, _Float16* __restrict__ out) {
  const int row = blockIdx.x;
  const float* xr = x + (size_t)row * C_;
  const int t = threadIdx.x;
  float v0 = xr[t], v1 = xr[t + 256], v2 = xr[t + 512];
  float s = v0 + v1 + v2;
  float q = v0 * v0 + v1 * v1 + v2 * v2;
#pragma unroll
  for (int m = 1; m < 64; m <<= 1) { s += __shfl_xor(s, m); q += __shfl_xor(q, m); }
  __shared__ float ls[4], lq[4];
  const int w = t >> 6, lane = t & 63;
  if (lane == 0) { ls[w] = s; lq[w] = q; }
  __syncthreads();
  s = ls[0] + ls[1] + ls[2] + ls[3];
  q = lq[0] + lq[1] + lq[2] + lq[3];
  const float mean = s * (1.f / C_);
  const float rstd = rsqrtf(q * (1.f / C_) - mean * mean + EPS_);
  _Float16* orow = out + (size_t)row * C_;
  orow[t]       = (_Float16)((v0 - mean) * rstd * g[t]       + b[t]);
  orow[t + 256] = (_Float16)((v1 - mean) * rstd * g[t + 256] + b[t + 256]);
  orow[t + 512] = (_Float16)((v2 - mean) * rstd * g[t + 512] + b[t + 512]);
}

// ------- residual + LayerNorm 2.  If r16 != nullptr, residual saved as f16
// (FFN2 then writes out = r16 + val, no fp32 RMW); else fp32 out (R13 path).
__global__ __launch_bounds__(256)
void resln2_kernel(const float* __restrict__ x, const _Float16* __restrict__ o,
                   const float* __restrict__ g, const float* __restrict__ bb,
                   float* __restrict__ xr_out, _Float16* __restrict__ r16,
                   _Float16* __restrict__ h) {
  const int row = blockIdx.x;
  const float* xp = x + (size_t)row * C_;
  const _Float16* op = o + (size_t)row * C_;
  const int t = threadIdx.x;
  float v[3]; float s = 0.f, q = 0.f;
#pragma unroll
  for (int i = 0; i < 3; i++) {
    int c = t + i * 256;
    v[i] = xp[c] + (float)op[c];
    s += v[i]; q += v[i] * v[i];
  }
#pragma unroll
  for (int m = 1; m < 64; m <<= 1) { s += __shfl_xor(s, m); q += __shfl_xor(q, m); }
  __shared__ float ls[4], lq[4];
  const int w = t >> 6, lane = t & 63;
  if (lane == 0) { ls[w] = s; lq[w] = q; }
  __syncthreads();
  s = ls[0] + ls[1] + ls[2] + ls[3];
  q = lq[0] + lq[1] + lq[2] + lq[3];
  const float mean = s * (1.f / C_);
  const float rstd = rsqrtf(q * (1.f / C_) - mean * mean + EPS_);
#pragma unroll
  for (int i = 0; i < 3; i++) {
    int c = t + i * 256;
    if (r16) r16[(size_t)row * C_ + c] = (_Float16)v[i];
    else     xr_out[(size_t)row * C_ + c] = v[i];
    h[(size_t)row * C_ + c] = (_Float16)((v[i] - mean) * rstd * g[c] + bb[c]);
  }
}

// ---------------- merged fp32 -> f16 weight cast ----------------
#define SZ_CC (C_ * C_)
#define SZ_CF (FFC * C_)
__global__ void cast_all_kernel(const float* __restrict__ Wq, const float* __restrict__ Wk,
                                const float* __restrict__ Wv, const float* __restrict__ W1,
                                const float* __restrict__ W2,
                                _Float16* __restrict__ oq, _Float16* __restrict__ ok,
                                _Float16* __restrict__ ov, _Float16* __restrict__ o1,
                                _Float16* __restrict__ o2) {
  const int total = 3 * SZ_CC + 2 * SZ_CF;
  int i = blockIdx.x * 256 + threadIdx.x;
  int stride = gridDim.x * 256;
  for (; i < total; i += stride) {
    if (i < SZ_CC)                     oq[i] = (_Float16)Wq[i];
    else if (i < 2 * SZ_CC)            ok[i - SZ_CC] = (_Float16)Wk[i - SZ_CC];
    else if (i < 3 * SZ_CC)            ov[i - 2 * SZ_CC] = (_Float16)Wv[i - 2 * SZ_CC];
    else if (i < 3 * SZ_CC + SZ_CF)    o1[i - 3 * SZ_CC] = (_Float16)W1[i - 3 * SZ_CC];
    else                               o2[i - 3 * SZ_CC - SZ_CF] = (_Float16)W2[i - 3 * SZ_CC - SZ_CF];
  }
}

// ---------------- V transpose: vbuf[b*256+kv][c] -> vT[b][c][kv] ----------------
__global__ __launch_bounds__(256)
void vtrans_kernel(const _Float16* __restrict__ vbuf, _Float16* __restrict__ vT) {
  const int b = blockIdx.z;
  const int c = blockIdx.y * 256 + threadIdx.x;
  const int kvb = blockIdx.x * 64;
#pragma unroll
  for (int kk = 0; kk < 8; kk++) {
    int kv0 = kvb + kk * 8;
    f16x8 v;
#pragma unroll
    for (int j = 0; j < 8; j++)
      v[j] = vbuf[(size_t)((b << 8) + kv0 + j) * C_ + c];
    *(f16x8*)(vT + ((size_t)(b * C_ + c) << 8) + kv0) = v;
  }
}

// ---------------- fused depthwise conv + ELU + BN for q,k,v ----------------
struct DwP { const float *w, *bias, *g, *b, *m, *v; };

__device__ __forceinline__ float elu_f(float x) {
  return x > 0.f ? x : __expf(x) - 1.f;
}

__global__ __launch_bounds__(384)
void dw_fused_kernel(const _Float16* __restrict__ xn, DwP pq, DwP pk, DwP pv,
                     _Float16* __restrict__ oq, _Float16* __restrict__ ok,
                     _Float16* __restrict__ ov) {
  const int i = blockIdx.x;                  // kv row 0..15
  const int jq = blockIdx.y;                 // j quarter 0..3
  const int b = blockIdx.z;
  const int c0 = 2 * threadIdx.x;            // channel pair
  const _Float16* xb = xn + (size_t)b * NQ * C_ + c0;

  float wqx[9], wqy[9], wkx[9], wky[9], wvx[9], wvy[9];
#pragma unroll
  for (int u = 0; u < 9; u++) {
    wqx[u] = pq.w[c0 * 9 + u]; wqy[u] = pq.w[(c0 + 1) * 9 + u];
    wkx[u] = pk.w[c0 * 9 + u]; wky[u] = pk.w[(c0 + 1) * 9 + u];
    wvx[u] = pv.w[c0 * 9 + u]; wvy[u] = pv.w[(c0 + 1) * 9 + u];
  }
  const float skqx = rsqrtf(pq.v[c0] + EPS_) * pq.g[c0], bnqx = pq.b[c0] - pq.m[c0] * skqx;
  const float skqy = rsqrtf(pq.v[c0+1] + EPS_) * pq.g[c0+1], bnqy = pq.b[c0+1] - pq.m[c0+1] * skqy;
  const float skkx = rsqrtf(pk.v[c0] + EPS_) * pk.g[c0], bnkx = pk.b[c0] - pk.m[c0] * skkx;
  const float skky = rsqrtf(pk.v[c0+1] + EPS_) * pk.g[c0+1], bnky = pk.b[c0+1] - pk.m[c0+1] * skky;
  const float skvx = rsqrtf(pv.v[c0] + EPS_) * pv.g[c0], bnvx = pv.b[c0] - pv.m[c0] * skvx;
  const float skvy = rsqrtf(pv.v[c0+1] + EPS_) * pv.g[c0+1], bnvy = pv.b[c0+1] - pv.m[c0+1] * skvy;
  const float cbqx = pq.bias[c0], cbqy = pq.bias[c0+1];
  const float cbkx = pk.bias[c0], cbky = pk.bias[c0+1];
  const float cbvx = pv.bias[c0], cbvy = pv.bias[c0+1];

  float tx[5][5], ty[5][5];
  auto ldc = [&](int s, int iw) {
    const bool cv = (iw >= 0 && iw < 32);
#pragma unroll
    for (int u = 0; u < 5; u++) {
      int ih = 2 * i - 1 + u;
      if (cv && ih >= 0 && ih < 32) {
        f16x2 p = *(const f16x2*)&xb[(size_t)(ih * 32 + iw) * C_];
        tx[u][s] = (float)p[0]; ty[u][s] = (float)p[1];
      } else { tx[u][s] = 0.f; ty[u][s] = 0.f; }
    }
  };

  const int j0 = jq * 4;
#pragma unroll
  for (int jj = 0; jj < 4; jj++) {
    const int j = j0 + jj;
    if (jj == 0) {
      ldc(0, 2 * j0 - 1); ldc(1, 2 * j0); ldc(2, 2 * j0 + 1);
      ldc(3, 2 * j0 + 2); ldc(4, 2 * j0 + 3);
    } else {
#pragma unroll
      for (int u = 0; u < 5; u++) {
        tx[u][0] = tx[u][2]; tx[u][1] = tx[u][3]; tx[u][2] = tx[u][4];
        ty[u][0] = ty[u][2]; ty[u][1] = ty[u][3]; ty[u][2] = ty[u][4];
      }
      ldc(3, 2 * j + 2); ldc(4, 2 * j + 3);
    }
    float akx = cbkx, aky = cbky, avx = cbvx, avy = cbvy;
#pragma unroll
    for (int u = 0; u < 3; u++)
#pragma unroll
      for (int vv = 0; vv < 3; vv++) {
        akx += tx[u][vv] * wkx[u * 3 + vv]; aky += ty[u][vv] * wky[u * 3 + vv];
        avx += tx[u][vv] * wvx[u * 3 + vv]; avy += ty[u][vv] * wvy[u * 3 + vv];
      }
    f16x2 kv2, vv2;
    kv2[0] = (_Float16)(elu_f(akx) * skkx + bnkx);
    kv2[1] = (_Float16)(elu_f(aky) * skky + bnky);
    vv2[0] = (_Float16)(elu_f(avx) * skvx + bnvx);
    vv2[1] = (_Float16)(elu_f(avy) * skvy + bnvy);
    *(f16x2*)&ok[((size_t)b * NKV + i * 16 + j) * C_ + c0] = kv2;
    *(f16x2*)&ov[((size_t)b * NKV + i * 16 + j) * C_ + c0] = vv2;
#pragma unroll
    for (int a = 0; a < 2; a++)
#pragma unroll
      for (int b2 = 0; b2 < 2; b2++) {
        float aqx = cbqx, aqy = cbqy;
#pragma unroll
        for (int u = 0; u < 3; u++)
#pragma unroll
          for (int vv = 0; vv < 3; vv++) {
            aqx += tx[a + u][b2 + vv] * wqx[u * 3 + vv];
            aqy += ty[a + u][b2 + vv] * wqy[u * 3 + vv];
          }
        f16x2 q2;
        q2[0] = (_Float16)(elu_f(aqx) * skqx + bnqx);
        q2[1] = (_Float16)(elu_f(aqy) * skqy + bnqy);
        *(f16x2*)&oq[((size_t)b * NQ + (2 * i + a) * 32 + (2 * j + b2)) * C_ + c0] = q2;
      }
  }
}

// ---------------- 128x128 GEMM core (R8/R13-proven; session optimum) -------
__device__ __forceinline__ void stage_tile(const _Float16* __restrict__ src, int ldk,
                                           int row0, int kt, _Float16* lds, int w, int lane) {
#pragma unroll
  for (int it = 0; it < 4; it++) {
    int cid = (it * 4 + w) * 64 + lane;      // 0..1023 16B-chunks
    int row = cid >> 3, kg = cid & 7;
    int kgs = kg ^ (row & 7);                // inverse-swizzled global source
    const _Float16* g = src + (size_t)(row0 + row) * ldk + kt * 64 + kgs * 8;
    gload_lds16((const void*)g, (void*)((char*)lds + (it * 4 + w) * 1024));
  }
}

template <int EPI>  // 0: ->f16  1: bias+GELU ->f16  2: fp32 out (resid16+val or +=)
__device__ __forceinline__
void gemm_core(const _Float16* __restrict__ A, const _Float16* __restrict__ Bw,
               const float* __restrict__ bias,
               _Float16* __restrict__ outh, float* __restrict__ outf,
               const _Float16* __restrict__ resid,
               int N, int K, int m0, int n0) {
  __shared__ __align__(16) _Float16 As[128 * 64];
  __shared__ __align__(16) _Float16 Bs[128 * 64];
  const int tid = threadIdx.x, w = tid >> 6, lane = tid & 63;
  const int wm = w >> 1, wn = w & 1;

  f32x4 acc[4][4];
#pragma unroll
  for (int i = 0; i < 4; i++)
#pragma unroll
    for (int j = 0; j < 4; j++)
#pragma unroll
      for (int r = 0; r < 4; r++) acc[i][j][r] = 0.f;

  const int NKT = K >> 6;
  for (int kt = 0; kt < NKT; kt++) {
    stage_tile(A, K, m0, kt, As, w, lane);
    stage_tile(Bw, K, n0, kt, Bs, w, lane);
    __syncthreads();
    f16x8 af[4][2], bfr[4][2];
#pragma unroll
    for (int mi = 0; mi < 4; mi++)
#pragma unroll
      for (int kh = 0; kh < 2; kh++) {
        int row = wm * 64 + mi * 16 + (lane & 15);
        int kg = kh * 4 + (lane >> 4);
        af[mi][kh] = *(const f16x8*)&As[row * 64 + ((kg ^ (row & 7)) << 3)];
      }
#pragma unroll
    for (int ni = 0; ni < 4; ni++)
#pragma unroll
      for (int kh = 0; kh < 2; kh++) {
        int row = wn * 64 + ni * 16 + (lane & 15);
        int kg = kh * 4 + (lane >> 4);
        bfr[ni][kh] = *(const f16x8*)&Bs[row * 64 + ((kg ^ (row & 7)) << 3)];
      }
    __builtin_amdgcn_s_setprio(1);
#pragma unroll
    for (int mi = 0; mi < 4; mi++)
#pragma unroll
      for (int ni = 0; ni < 4; ni++)
#pragma unroll
        for (int kh = 0; kh < 2; kh++)
          acc[mi][ni] = __builtin_amdgcn_mfma_f32_16x16x32_f16(af[mi][kh], bfr[ni][kh],
                                                               acc[mi][ni], 0, 0, 0);
    __builtin_amdgcn_s_setprio(0);
    __syncthreads();
  }
#pragma unroll
  for (int mi = 0; mi < 4; mi++)
#pragma unroll
    for (int ni = 0; ni < 4; ni++) {
      int col = n0 + wn * 64 + ni * 16 + (lane & 15);
      float bv = bias[col];
#pragma unroll
      for (int r = 0; r < 4; r++) {
        int rowg = m0 + wm * 64 + mi * 16 + (lane >> 4) * 4 + r;
        float val = acc[mi][ni][r] + bv;
        size_t idx = (size_t)rowg * N + col;
        if (EPI == 0)      outh[idx] = (_Float16)val;
        else if (EPI == 1) outh[idx] = (_Float16)gelu_f(val);
        else {
          if (resid) outf[idx] = (float)resid[idx] + val;   // pure write path
          else       outf[idx] += val;                       // fallback
        }
      }
    }
}

template <int EPI>
__global__ __launch_bounds__(256, 3)
void gemm_f16(const _Float16* __restrict__ A, const _Float16* __restrict__ Bw,
              const float* __restrict__ bias,
              _Float16* __restrict__ outh, float* __restrict__ outf,
              const _Float16* __restrict__ resid,
              int M, int N, int K, int NT) {
  const int nwg = gridDim.x, d = blockIdx.x;
  const int o = (d & 7) * (nwg >> 3) + (d >> 3);
  gemm_core<EPI>(A, Bw, bias, outh, outf, resid, N, K, (o / NT) * 128, (o % NT) * 128);
}

// fused K-proj + V-proj
__global__ __launch_bounds__(256, 3)
void gemm_kv(const _Float16* __restrict__ Ak, const _Float16* __restrict__ Wk,
             const float* __restrict__ bk, _Float16* __restrict__ outk,
             const _Float16* __restrict__ Av, const _Float16* __restrict__ Wv,
             const float* __restrict__ bv, _Float16* __restrict__ outv) {
  const int nwg = gridDim.x, d = blockIdx.x;
  int o = (d & 7) * (nwg >> 3) + (d >> 3);
  const bool isv = o >= 384;
  if (isv) o -= 384;
  const int m0 = (o / 6) * 128, n0 = (o % 6) * 128;
  if (isv) gemm_core<0>(Av, Wv, bv, outv, nullptr, nullptr, C_, C_, m0, n0);
  else     gemm_core<0>(Ak, Wk, bk, outk, nullptr, nullptr, C_, C_, m0, n0);
}

// ---------------- attention: softmax(q k^T / 8) v ----------------
__global__ __launch_bounds__(512, 2)
void attn_kernel(const _Float16* __restrict__ Q, const _Float16* __restrict__ Kb,
                 const _Float16* __restrict__ vT, _Float16* __restrict__ O) {
  __shared__ __align__(16) _Float16 Klds[256 * 64];   // [kv][d], chunk^=(kv&7)
  __shared__ __align__(16) _Float16 Vt[64 * 256];     // [d][kv], chunk^=(d&7)
  const int tid = threadIdx.x, w = tid >> 6, lane = tid & 63;
  const int hi = lane >> 4, lo = lane & 15;
  const int half = blockIdx.x & 1;
  const int h = (blockIdx.x >> 1) % NH_;
  const int b = blockIdx.x / (2 * NH_);

  const _Float16* qp = Q + (size_t)b * NQ * C_ + h * HD_;
  const _Float16* kp = Kb + (size_t)b * NKV * C_ + h * HD_;
  const _Float16* vp = vT + ((size_t)(b * C_ + h * HD_) << 8);

#pragma unroll
  for (int i = 0; i < 4; i++) {
    int cid = i * 512 + w * 64 + lane;
    int row = cid >> 3, kg = cid & 7;
    const _Float16* g = kp + (size_t)row * C_ + ((kg ^ (row & 7)) << 3);
    gload_lds16((const void*)g, (void*)((char*)Klds + (i * 512 + w * 64) * 16));
  }
#pragma unroll
  for (int i = 0; i < 4; i++) {
    int cid = i * 512 + w * 64 + lane;
    int row = cid >> 5, kg = cid & 31;
    const _Float16* g = vp + ((size_t)row << 8) + ((kg ^ (row & 7)) << 3);
    gload_lds16((const void*)g, (void*)((char*)Vt + (i * 512 + w * 64) * 16));
  }
  __syncthreads();

#pragma unroll
  for (int ti = 0; ti < 4; ti++) {
    const int q0 = half * 512 + w * 64 + ti * 16;
    f16x8 qf[2];
#pragma unroll
    for (int kh = 0; kh < 2; kh++)
      qf[kh] = *(const f16x8*)(qp + (size_t)(q0 + lo) * C_ + kh * 32 + hi * 8);
    f32x4 S[16];
#pragma unroll
    for (int nt = 0; nt < 16; nt++) {
      f32x4 s; s[0] = 0.f; s[1] = 0.f; s[2] = 0.f; s[3] = 0.f;
      const _Float16* krow = &Klds[(nt * 16 + lo) * 64];
#pragma unroll
      for (int kh = 0; kh < 2; kh++) {
        f16x8 kf = *(const f16x8*)&krow[((kh * 4 + hi) ^ (lo & 7)) << 3];
        s = __builtin_amdgcn_mfma_f32_16x16x32_f16(kf, qf[kh], s, 0, 0, 0);
      }
      S[nt] = s;
    }
    float mx = -1e30f;
#pragma unroll
    for (int nt = 0; nt < 16; nt++)
#pragma unroll
      for (int r = 0; r < 4; r++) { S[nt][r] *= 0.125f; mx = fmaxf(mx, S[nt][r]); }
    mx = fmaxf(mx, __shfl_xor(mx, 16));
    mx = fmaxf(mx, __shfl_xor(mx, 32));
    float sum = 0.f;
#pragma unroll
    for (int nt = 0; nt < 16; nt++)
#pragma unroll
      for (int r = 0; r < 4; r++) { float e = __expf(S[nt][r] - mx); S[nt][r] = e; sum += e; }
    sum += __shfl_xor(sum, 16);
    sum += __shfl_xor(sum, 32);
    const float inv = 1.f / sum;
    f16x8 pa8[8];
#pragma unroll
    for (int ntp = 0; ntp < 8; ntp++)
#pragma unroll
      for (int r = 0; r < 4; r++) {
        pa8[ntp][r]     = (_Float16)(S[2 * ntp][r] * inv);
        pa8[ntp][4 + r] = (_Float16)(S[2 * ntp + 1][r] * inv);
      }
    f32x4 acc[4];
#pragma unroll
    for (int dt = 0; dt < 4; dt++) { acc[dt][0] = 0.f; acc[dt][1] = 0.f; acc[dt][2] = 0.f; acc[dt][3] = 0.f; }
#pragma unroll
    for (int dt = 0; dt < 4; dt++) {
      const int d = dt * 16 + lo, sw = d & 7;
      const _Float16* vrow = &Vt[d * 256 + 4 * (hi & 1)];
#pragma unroll
      for (int ntp = 0; ntp < 8; ntp++) {
        f16x4 v0 = *(const f16x4*)&vrow[((4 * ntp + (hi >> 1)) ^ sw) << 3];
        f16x4 v1 = *(const f16x4*)&vrow[((4 * ntp + 2 + (hi >> 1)) ^ sw) << 3];
        f16x8 vt8;
#pragma unroll
        for (int r = 0; r < 4; r++) { vt8[r] = v0[r]; vt8[4 + r] = v1[r]; }
        acc[dt] = __builtin_amdgcn_mfma_f32_16x16x32_f16(pa8[ntp], vt8, acc[dt], 0, 0, 0);
      }
    }
#pragma unroll
    for (int dt = 0; dt < 4; dt++)
#pragma unroll
      for (int r = 0; r < 4; r++)
        O[(size_t)(b * NQ + q0 + 4 * hi + r) * C_ + h * HD_ + dt * 16 + lo] = (_Float16)acc[dt][r];
  }
}

// ---------------- host launcher ----------------
extern "C" void kernel_launch(void* const* d_in, const int* in_sizes, int n_in,
                              void* d_out, int out_size, void* d_ws, size_t ws_size,
                              hipStream_t stream) {
  (void)in_sizes; (void)n_in; (void)out_size;
  const float* x    = (const float*)d_in[0];
  const float* ln1g = (const float*)d_in[1];
  const float* ln1b = (const float*)d_in[2];
  DwP pq { (const float*)d_in[3], (const float*)d_in[4], (const float*)d_in[5],
           (const float*)d_in[6], (const float*)d_in[7], (const float*)d_in[8] };
  const float* Wq = (const float*)d_in[9];  const float* bq = (const float*)d_in[10];
  DwP pk { (const float*)d_in[11], (const float*)d_in[12], (const float*)d_in[13],
           (const float*)d_in[14], (const float*)d_in[15], (const float*)d_in[16] };
  const float* Wk = (const float*)d_in[17]; const float* bk = (const float*)d_in[18];
  DwP pv { (const float*)d_in[19], (const float*)d_in[20], (const float*)d_in[21],
           (const float*)d_in[22], (const float*)d_in[23], (const float*)d_in[24] };
  const float* Wv = (const float*)d_in[25]; const float* bv = (const float*)d_in[26];
  const float* ln2g = (const float*)d_in[27];
  const float* ln2b = (const float*)d_in[28];
  const float* W1 = (const float*)d_in[29]; const float* b1 = (const float*)d_in[30];
  const float* W2 = (const float*)d_in[31]; const float* b2 = (const float*)d_in[32];

  char* ws = (char*)d_ws;
  _Float16* gbuf = (_Float16*)(ws + 0);              // per-chunk 16384*3072*2 = 100663296
  _Float16* xn   = (_Float16*)(ws + 0);              // 48MB
  _Float16* qb   = (_Float16*)(ws + 50331648);       // 48MB
  _Float16* tk   = (_Float16*)(ws + 100663296);      // 12MB
  _Float16* tv   = (_Float16*)(ws + 113246208);      // 12MB (reused as vT)
  _Float16* vTb  = tv;
  _Float16* kb   = (_Float16*)(ws + 125829120);      // 12MB
  _Float16* vbuf = (_Float16*)(ws + 138412032);      // 12MB
  _Float16* o    = (_Float16*)(ws + 150994944);      // 48MB, ends 201326592
  _Float16* tq   = (_Float16*)(ws + 201326592);      // 48MB (reused as hb)
  _Float16* hb   = tq;
  _Float16* wqh  = (_Float16*)(ws + 251658240);
  _Float16* wkh  = (_Float16*)(ws + 252837888);
  _Float16* wvh  = (_Float16*)(ws + 254017536);
  _Float16* w1h  = (_Float16*)(ws + 255197184);
  _Float16* w2h  = (_Float16*)(ws + 259915776);      // ends 264634368 (~252MB)
  // optional f16 residual buffer (48MB) above everything else
  const size_t R16_OFF = 264634368;
  const size_t R16_SZ  = (size_t)NB * NQ * C_ * 2;   // 50331648
  _Float16* r16 = (ws_size >= R16_OFF + R16_SZ) ? (_Float16*)(ws + R16_OFF) : nullptr;
  float* out = (float*)d_out;

  ln_fwd_kernel<<<NB * NQ, 256, 0, stream>>>(x, ln1g, ln1b, xn);
  cast_all_kernel<<<2048, 256, 0, stream>>>(Wq, Wk, Wv, W1, W2, wqh, wkh, wvh, w1h, w2h);
  dw_fused_kernel<<<dim3(16, 4, NB), 384, 0, stream>>>(xn, pq, pk, pv, tq, tk, tv);
  gemm_f16<0><<<1536, 256, 0, stream>>>(tq, wqh, bq, qb, nullptr, nullptr, NB * NQ, C_, C_, 6);
  gemm_kv<<<768, 256, 0, stream>>>(tk, wkh, bk, kb, tv, wvh, bv, vbuf);
  vtrans_kernel<<<dim3(4, 3, NB), 256, 0, stream>>>(vbuf, vTb);
  attn_kernel<<<NB * NH_ * 2, 512, 0, stream>>>(qb, kb, vTb, o);
  resln2_kernel<<<NB * NQ, 256, 0, stream>>>(x, o, ln2g, ln2b, out, r16, hb);
  // FFN in 2 M-halves: per half gbuf = 100MB -> L3-resident between FFN1
  // write and FFN2 read (unchunked gbuf = 201MB spilled L3: R15 FFN2 FETCH
  // 174MB). Grids stay %8==0 and >= 3 blocks/CU coverage.
  for (int mc = 0; mc < 2; mc++) {
    const size_t roff = (size_t)mc * 16384 * C_;
    gemm_f16<1><<<3072, 256, 0, stream>>>(hb + roff, w1h, b1, gbuf, nullptr, nullptr,
                                          16384, FFC, C_, 24);
    gemm_f16<2><<<768, 256, 0, stream>>>(gbuf, w2h, b2, nullptr, out + roff,
                                         r16 ? r16 + roff : nullptr, 16384, C_, FFC, 6);
  }
}

// Round 18
// 782.287 us; speedup vs baseline: 1.0068x; 1.0068x over previous
//
#include <hip/hip_runtime.h>
#include <math.h>

#define NB   32
#define C_   768
#define NQ   1024
#define NKV  256
#define NH_  12
#define HD_  64
#define FFC  3072
#define EPS_ 1e-5f

typedef __attribute__((ext_vector_type(8))) _Float16 f16x8;
typedef __attribute__((ext_vector_type(4))) _Float16 f16x4;
typedef __attribute__((ext_vector_type(2))) _Float16 f16x2;
typedef __attribute__((ext_vector_type(4))) float    f32x4;

__device__ __forceinline__ void gload_lds16(const void* g, void* l) {
  __builtin_amdgcn_global_load_lds((const __attribute__((address_space(1))) void*)g,
                                   (__attribute__((address_space(3))) void*)l, 16, 0, 0);
}

// gelu tanh-approx (sigmoid form), ~5 VALU ops vs ~30 for erff (R8 win).
__device__ __forceinline__ float gelu_f(float x) {
  return x / (1.f + __expf(-1.5957691216f * (x + 0.044715f * x * x * x)));
}

// ---------------- LayerNorm 1 (f16 out; only dw consumes it) ----------------
__global__ __launch_bounds__(256)
void ln_fwd_kernel(const float* __restrict__ x, const float* __restrict__ g,
                   const float* __restrict__ b, _Float16* __restrict__ out) {
  const int row = blockIdx.x;
  const float* xr = x + (size_t)row * C_;
  const int t = threadIdx.x;
  float v0 = xr[t], v1 = xr[t + 256], v2 = xr[t + 512];
  float s = v0 + v1 + v2;
  float q = v0 * v0 + v1 * v1 + v2 * v2;
#pragma unroll
  for (int m = 1; m < 64; m <<= 1) { s += __shfl_xor(s, m); q += __shfl_xor(q, m); }
  __shared__ float ls[4], lq[4];
  const int w = t >> 6, lane = t & 63;
  if (lane == 0) { ls[w] = s; lq[w] = q; }
  __syncthreads();
  s = ls[0] + ls[1] + ls[2] + ls[3];
  q = lq[0] + lq[1] + lq[2] + lq[3];
  const float mean = s * (1.f / C_);
  const float rstd = rsqrtf(q * (1.f / C_) - mean * mean + EPS_);
  _Float16* orow = out + (size_t)row * C_;
  orow[t]       = (_Float16)((v0 - mean) * rstd * g[t]       + b[t]);
  orow[t + 256] = (_Float16)((v1 - mean) * rstd * g[t + 256] + b[t + 256]);
  orow[t + 512] = (_Float16)((v2 - mean) * rstd * g[t + 512] + b[t + 512]);
}

// ------- residual + LayerNorm 2.  If r16 != nullptr, residual saved as f16
// (FFN2 then writes out = r16 + val, no fp32 RMW); else fp32 out (R13 path).
__global__ __launch_bounds__(256)
void resln2_kernel(const float* __restrict__ x, const _Float16* __restrict__ o,
                   const float* __restrict__ g, const float* __restrict__ bb,
                   float* __restrict__ xr_out, _Float16* __restrict__ r16,
                   _Float16* __restrict__ h) {
  const int row = blockIdx.x;
  const float* xp = x + (size_t)row * C_;
  const _Float16* op = o + (size_t)row * C_;
  const int t = threadIdx.x;
  float v[3]; float s = 0.f, q = 0.f;
#pragma unroll
  for (int i = 0; i < 3; i++) {
    int c = t + i * 256;
    v[i] = xp[c] + (float)op[c];
    s += v[i]; q += v[i] * v[i];
  }
#pragma unroll
  for (int m = 1; m < 64; m <<= 1) { s += __shfl_xor(s, m); q += __shfl_xor(q, m); }
  __shared__ float ls[4], lq[4];
  const int w = t >> 6, lane = t & 63;
  if (lane == 0) { ls[w] = s; lq[w] = q; }
  __syncthreads();
  s = ls[0] + ls[1] + ls[2] + ls[3];
  q = lq[0] + lq[1] + lq[2] + lq[3];
  const float mean = s * (1.f / C_);
  const float rstd = rsqrtf(q * (1.f / C_) - mean * mean + EPS_);
#pragma unroll
  for (int i = 0; i < 3; i++) {
    int c = t + i * 256;
    if (r16) r16[(size_t)row * C_ + c] = (_Float16)v[i];
    else     xr_out[(size_t)row * C_ + c] = v[i];
    h[(size_t)row * C_ + c] = (_Float16)((v[i] - mean) * rstd * g[c] + bb[c]);
  }
}

// ---------------- merged fp32 -> f16 weight cast ----------------
#define SZ_CC (C_ * C_)
#define SZ_CF (FFC * C_)
__global__ void cast_all_kernel(const float* __restrict__ Wq, const float* __restrict__ Wk,
                                const float* __restrict__ Wv, const float* __restrict__ W1,
                                const float* __restrict__ W2,
                                _Float16* __restrict__ oq, _Float16* __restrict__ ok,
                                _Float16* __restrict__ ov, _Float16* __restrict__ o1,
                                _Float16* __restrict__ o2) {
  const int total = 3 * SZ_CC + 2 * SZ_CF;
  int i = blockIdx.x * 256 + threadIdx.x;
  int stride = gridDim.x * 256;
  for (; i < total; i += stride) {
    if (i < SZ_CC)                     oq[i] = (_Float16)Wq[i];
    else if (i < 2 * SZ_CC)            ok[i - SZ_CC] = (_Float16)Wk[i - SZ_CC];
    else if (i < 3 * SZ_CC)            ov[i - 2 * SZ_CC] = (_Float16)Wv[i - 2 * SZ_CC];
    else if (i < 3 * SZ_CC + SZ_CF)    o1[i - 3 * SZ_CC] = (_Float16)W1[i - 3 * SZ_CC];
    else                               o2[i - 3 * SZ_CC - SZ_CF] = (_Float16)W2[i - 3 * SZ_CC - SZ_CF];
  }
}

// ---------------- V transpose: vbuf[b*256+kv][c] -> vT[b][c][kv] ----------------
__global__ __launch_bounds__(256)
void vtrans_kernel(const _Float16* __restrict__ vbuf, _Float16* __restrict__ vT) {
  const int b = blockIdx.z;
  const int c = blockIdx.y * 256 + threadIdx.x;
  const int kvb = blockIdx.x * 64;
#pragma unroll
  for (int kk = 0; kk < 8; kk++) {
    int kv0 = kvb + kk * 8;
    f16x8 v;
#pragma unroll
    for (int j = 0; j < 8; j++)
      v[j] = vbuf[(size_t)((b << 8) + kv0 + j) * C_ + c];
    *(f16x8*)(vT + ((size_t)(b * C_ + c) << 8) + kv0) = v;
  }
}

// ---------------- fused depthwise conv + ELU + BN for q,k,v ----------------
struct DwP { const float *w, *bias, *g, *b, *m, *v; };

__device__ __forceinline__ float elu_f(float x) {
  return x > 0.f ? x : __expf(x) - 1.f;
}

__global__ __launch_bounds__(384)
void dw_fused_kernel(const _Float16* __restrict__ xn, DwP pq, DwP pk, DwP pv,
                     _Float16* __restrict__ oq, _Float16* __restrict__ ok,
                     _Float16* __restrict__ ov) {
  const int i = blockIdx.x;                  // kv row 0..15
  const int jq = blockIdx.y;                 // j quarter 0..3
  const int b = blockIdx.z;
  const int c0 = 2 * threadIdx.x;            // channel pair
  const _Float16* xb = xn + (size_t)b * NQ * C_ + c0;

  float wqx[9], wqy[9], wkx[9], wky[9], wvx[9], wvy[9];
#pragma unroll
  for (int u = 0; u < 9; u++) {
    wqx[u] = pq.w[c0 * 9 + u]; wqy[u] = pq.w[(c0 + 1) * 9 + u];
    wkx[u] = pk.w[c0 * 9 + u]; wky[u] = pk.w[(c0 + 1) * 9 + u];
    wvx[u] = pv.w[c0 * 9 + u]; wvy[u] = pv.w[(c0 + 1) * 9 + u];
  }
  const float skqx = rsqrtf(pq.v[c0] + EPS_) * pq.g[c0], bnqx = pq.b[c0] - pq.m[c0] * skqx;
  const float skqy = rsqrtf(pq.v[c0+1] + EPS_) * pq.g[c0+1], bnqy = pq.b[c0+1] - pq.m[c0+1] * skqy;
  const float skkx = rsqrtf(pk.v[c0] + EPS_) * pk.g[c0], bnkx = pk.b[c0] - pk.m[c0] * skkx;
  const float skky = rsqrtf(pk.v[c0+1] + EPS_) * pk.g[c0+1], bnky = pk.b[c0+1] - pk.m[c0+1] * skky;
  const float skvx = rsqrtf(pv.v[c0] + EPS_) * pv.g[c0], bnvx = pv.b[c0] - pv.m[c0] * skvx;
  const float skvy = rsqrtf(pv.v[c0+1] + EPS_) * pv.g[c0+1], bnvy = pv.b[c0+1] - pv.m[c0+1] * skvy;
  const float cbqx = pq.bias[c0], cbqy = pq.bias[c0+1];
  const float cbkx = pk.bias[c0], cbky = pk.bias[c0+1];
  const float cbvx = pv.bias[c0], cbvy = pv.bias[c0+1];

  float tx[5][5], ty[5][5];
  auto ldc = [&](int s, int iw) {
    const bool cv = (iw >= 0 && iw < 32);
#pragma unroll
    for (int u = 0; u < 5; u++) {
      int ih = 2 * i - 1 + u;
      if (cv && ih >= 0 && ih < 32) {
        f16x2 p = *(const f16x2*)&xb[(size_t)(ih * 32 + iw) * C_];
        tx[u][s] = (float)p[0]; ty[u][s] = (float)p[1];
      } else { tx[u][s] = 0.f; ty[u][s] = 0.f; }
    }
  };

  const int j0 = jq * 4;
#pragma unroll
  for (int jj = 0; jj < 4; jj++) {
    const int j = j0 + jj;
    if (jj == 0) {
      ldc(0, 2 * j0 - 1); ldc(1, 2 * j0); ldc(2, 2 * j0 + 1);
      ldc(3, 2 * j0 + 2); ldc(4, 2 * j0 + 3);
    } else {
#pragma unroll
      for (int u = 0; u < 5; u++) {
        tx[u][0] = tx[u][2]; tx[u][1] = tx[u][3]; tx[u][2] = tx[u][4];
        ty[u][0] = ty[u][2]; ty[u][1] = ty[u][3]; ty[u][2] = ty[u][4];
      }
      ldc(3, 2 * j + 2); ldc(4, 2 * j + 3);
    }
    float akx = cbkx, aky = cbky, avx = cbvx, avy = cbvy;
#pragma unroll
    for (int u = 0; u < 3; u++)
#pragma unroll
      for (int vv = 0; vv < 3; vv++) {
        akx += tx[u][vv] * wkx[u * 3 + vv]; aky += ty[u][vv] * wky[u * 3 + vv];
        avx += tx[u][vv] * wvx[u * 3 + vv]; avy += ty[u][vv] * wvy[u * 3 + vv];
      }
    f16x2 kv2, vv2;
    kv2[0] = (_Float16)(elu_f(akx) * skkx + bnkx);
    kv2[1] = (_Float16)(elu_f(aky) * skky + bnky);
    vv2[0] = (_Float16)(elu_f(avx) * skvx + bnvx);
    vv2[1] = (_Float16)(elu_f(avy) * skvy + bnvy);
    *(f16x2*)&ok[((size_t)b * NKV + i * 16 + j) * C_ + c0] = kv2;
    *(f16x2*)&ov[((size_t)b * NKV + i * 16 + j) * C_ + c0] = vv2;
#pragma unroll
    for (int a = 0; a < 2; a++)
#pragma unroll
      for (int b2 = 0; b2 < 2; b2++) {
        float aqx = cbqx, aqy = cbqy;
#pragma unroll
        for (int u = 0; u < 3; u++)
#pragma unroll
          for (int vv = 0; vv < 3; vv++) {
            aqx += tx[a + u][b2 + vv] * wqx[u * 3 + vv];
            aqy += ty[a + u][b2 + vv] * wqy[u * 3 + vv];
          }
        f16x2 q2;
        q2[0] = (_Float16)(elu_f(aqx) * skqx + bnqx);
        q2[1] = (_Float16)(elu_f(aqy) * skqy + bnqy);
        *(f16x2*)&oq[((size_t)b * NQ + (2 * i + a) * 32 + (2 * j + b2)) * C_ + c0] = q2;
      }
  }
}

// ---------------- 128x128 GEMM core (R8/R13-proven; session optimum) -------
// R17: staging source pointers hoisted to per-thread induction variables
// (+= 64 elems per K-tile) -- cuts the 64-bit addr-recompute chains that
// showed as VALUBusy 44% on FFN1 (epilogue gelu + addressing).
template <int EPI>  // 0: ->f16  1: bias+GELU ->f16  2: fp32 out (resid16+val or +=)
__device__ __forceinline__
void gemm_core(const _Float16* __restrict__ A, const _Float16* __restrict__ Bw,
               const float* __restrict__ bias,
               _Float16* __restrict__ outh, float* __restrict__ outf,
               const _Float16* __restrict__ resid,
               int N, int K, int m0, int n0) {
  __shared__ __align__(16) _Float16 As[128 * 64];
  __shared__ __align__(16) _Float16 Bs[128 * 64];
  const int tid = threadIdx.x, w = tid >> 6, lane = tid & 63;
  const int wm = w >> 1, wn = w & 1;

  // per-thread staging sources (kt=0), swizzle folded in; advance by 64/tile
  const _Float16* aSrc[4];
  const _Float16* bSrc[4];
  char* aDst[4];
  char* bDst[4];
#pragma unroll
  for (int it = 0; it < 4; it++) {
    int cid = (it * 4 + w) * 64 + lane;      // 0..1023 16B-chunks
    int row = cid >> 3, kg = cid & 7;
    int kgs = (kg ^ (row & 7)) << 3;
    aSrc[it] = A + (size_t)(m0 + row) * K + kgs;
    bSrc[it] = Bw + (size_t)(n0 + row) * K + kgs;
    aDst[it] = (char*)As + (it * 4 + w) * 1024;
    bDst[it] = (char*)Bs + (it * 4 + w) * 1024;
  }

  f32x4 acc[4][4];
#pragma unroll
  for (int i = 0; i < 4; i++)
#pragma unroll
    for (int j = 0; j < 4; j++)
#pragma unroll
      for (int r = 0; r < 4; r++) acc[i][j][r] = 0.f;

  const int NKT = K >> 6;
  for (int kt = 0; kt < NKT; kt++) {
#pragma unroll
    for (int it = 0; it < 4; it++) gload_lds16((const void*)aSrc[it], (void*)aDst[it]);
#pragma unroll
    for (int it = 0; it < 4; it++) gload_lds16((const void*)bSrc[it], (void*)bDst[it]);
#pragma unroll
    for (int it = 0; it < 4; it++) { aSrc[it] += 64; bSrc[it] += 64; }
    __syncthreads();
    f16x8 af[4][2], bfr[4][2];
#pragma unroll
    for (int mi = 0; mi < 4; mi++)
#pragma unroll
      for (int kh = 0; kh < 2; kh++) {
        int row = wm * 64 + mi * 16 + (lane & 15);
        int kg = kh * 4 + (lane >> 4);
        af[mi][kh] = *(const f16x8*)&As[row * 64 + ((kg ^ (row & 7)) << 3)];
      }
#pragma unroll
    for (int ni = 0; ni < 4; ni++)
#pragma unroll
      for (int kh = 0; kh < 2; kh++) {
        int row = wn * 64 + ni * 16 + (lane & 15);
        int kg = kh * 4 + (lane >> 4);
        bfr[ni][kh] = *(const f16x8*)&Bs[row * 64 + ((kg ^ (row & 7)) << 3)];
      }
    __builtin_amdgcn_s_setprio(1);
#pragma unroll
    for (int mi = 0; mi < 4; mi++)
#pragma unroll
      for (int ni = 0; ni < 4; ni++)
#pragma unroll
        for (int kh = 0; kh < 2; kh++)
          acc[mi][ni] = __builtin_amdgcn_mfma_f32_16x16x32_f16(af[mi][kh], bfr[ni][kh],
                                                               acc[mi][ni], 0, 0, 0);
    __builtin_amdgcn_s_setprio(0);
    __syncthreads();
  }
#pragma unroll
  for (int mi = 0; mi < 4; mi++)
#pragma unroll
    for (int ni = 0; ni < 4; ni++) {
      int col = n0 + wn * 64 + ni * 16 + (lane & 15);
      float bv = bias[col];
#pragma unroll
      for (int r = 0; r < 4; r++) {
        int rowg = m0 + wm * 64 + mi * 16 + (lane >> 4) * 4 + r;
        float val = acc[mi][ni][r] + bv;
        size_t idx = (size_t)rowg * N + col;
        if (EPI == 0)      outh[idx] = (_Float16)val;
        else if (EPI == 1) outh[idx] = (_Float16)gelu_f(val);
        else {
          if (resid) outf[idx] = (float)resid[idx] + val;   // pure write path
          else       outf[idx] += val;                       // fallback
        }
      }
    }
}

template <int EPI>
__global__ __launch_bounds__(256, 3)
void gemm_f16(const _Float16* __restrict__ A, const _Float16* __restrict__ Bw,
              const float* __restrict__ bias,
              _Float16* __restrict__ outh, float* __restrict__ outf,
              const _Float16* __restrict__ resid,
              int M, int N, int K, int NT) {
  const int nwg = gridDim.x, d = blockIdx.x;
  const int o = (d & 7) * (nwg >> 3) + (d >> 3);
  gemm_core<EPI>(A, Bw, bias, outh, outf, resid, N, K, (o / NT) * 128, (o % NT) * 128);
}

// fused K-proj + V-proj
__global__ __launch_bounds__(256, 3)
void gemm_kv(const _Float16* __restrict__ Ak, const _Float16* __restrict__ Wk,
             const float* __restrict__ bk, _Float16* __restrict__ outk,
             const _Float16* __restrict__ Av, const _Float16* __restrict__ Wv,
             const float* __restrict__ bv, _Float16* __restrict__ outv) {
  const int nwg = gridDim.x, d = blockIdx.x;
  int o = (d & 7) * (nwg >> 3) + (d >> 3);
  const bool isv = o >= 384;
  if (isv) o -= 384;
  const int m0 = (o / 6) * 128, n0 = (o % 6) * 128;
  if (isv) gemm_core<0>(Av, Wv, bv, outv, nullptr, nullptr, C_, C_, m0, n0);
  else     gemm_core<0>(Ak, Wk, bk, outk, nullptr, nullptr, C_, C_, m0, n0);
}

// ---------------- attention: softmax(q k^T / 8) v ----------------
__global__ __launch_bounds__(512, 2)
void attn_kernel(const _Float16* __restrict__ Q, const _Float16* __restrict__ Kb,
                 const _Float16* __restrict__ vT, _Float16* __restrict__ O) {
  __shared__ __align__(16) _Float16 Klds[256 * 64];   // [kv][d], chunk^=(kv&7)
  __shared__ __align__(16) _Float16 Vt[64 * 256];     // [d][kv], chunk^=(d&7)
  const int tid = threadIdx.x, w = tid >> 6, lane = tid & 63;
  const int hi = lane >> 4, lo = lane & 15;
  const int half = blockIdx.x & 1;
  const int h = (blockIdx.x >> 1) % NH_;
  const int b = blockIdx.x / (2 * NH_);

  const _Float16* qp = Q + (size_t)b * NQ * C_ + h * HD_;
  const _Float16* kp = Kb + (size_t)b * NKV * C_ + h * HD_;
  const _Float16* vp = vT + ((size_t)(b * C_ + h * HD_) << 8);

#pragma unroll
  for (int i = 0; i < 4; i++) {
    int cid = i * 512 + w * 64 + lane;
    int row = cid >> 3, kg = cid & 7;
    const _Float16* g = kp + (size_t)row * C_ + ((kg ^ (row & 7)) << 3);
    gload_lds16((const void*)g, (void*)((char*)Klds + (i * 512 + w * 64) * 16));
  }
#pragma unroll
  for (int i = 0; i < 4; i++) {
    int cid = i * 512 + w * 64 + lane;
    int row = cid >> 5, kg = cid & 31;
    const _Float16* g = vp + ((size_t)row << 8) + ((kg ^ (row & 7)) << 3);
    gload_lds16((const void*)g, (void*)((char*)Vt + (i * 512 + w * 64) * 16));
  }
  __syncthreads();

#pragma unroll
  for (int ti = 0; ti < 4; ti++) {
    const int q0 = half * 512 + w * 64 + ti * 16;
    f16x8 qf[2];
#pragma unroll
    for (int kh = 0; kh < 2; kh++)
      qf[kh] = *(const f16x8*)(qp + (size_t)(q0 + lo) * C_ + kh * 32 + hi * 8);
    f32x4 S[16];
#pragma unroll
    for (int nt = 0; nt < 16; nt++) {
      f32x4 s; s[0] = 0.f; s[1] = 0.f; s[2] = 0.f; s[3] = 0.f;
      const _Float16* krow = &Klds[(nt * 16 + lo) * 64];
#pragma unroll
      for (int kh = 0; kh < 2; kh++) {
        f16x8 kf = *(const f16x8*)&krow[((kh * 4 + hi) ^ (lo & 7)) << 3];
        s = __builtin_amdgcn_mfma_f32_16x16x32_f16(kf, qf[kh], s, 0, 0, 0);
      }
      S[nt] = s;
    }
    float mx = -1e30f;
#pragma unroll
    for (int nt = 0; nt < 16; nt++)
#pragma unroll
      for (int r = 0; r < 4; r++) { S[nt][r] *= 0.125f; mx = fmaxf(mx, S[nt][r]); }
    mx = fmaxf(mx, __shfl_xor(mx, 16));
    mx = fmaxf(mx, __shfl_xor(mx, 32));
    float sum = 0.f;
#pragma unroll
    for (int nt = 0; nt < 16; nt++)
#pragma unroll
      for (int r = 0; r < 4; r++) { float e = __expf(S[nt][r] - mx); S[nt][r] = e; sum += e; }
    sum += __shfl_xor(sum, 16);
    sum += __shfl_xor(sum, 32);
    const float inv = 1.f / sum;
    f16x8 pa8[8];
#pragma unroll
    for (int ntp = 0; ntp < 8; ntp++)
#pragma unroll
      for (int r = 0; r < 4; r++) {
        pa8[ntp][r]     = (_Float16)(S[2 * ntp][r] * inv);
        pa8[ntp][4 + r] = (_Float16)(S[2 * ntp + 1][r] * inv);
      }
    f32x4 acc[4];
#pragma unroll
    for (int dt = 0; dt < 4; dt++) { acc[dt][0] = 0.f; acc[dt][1] = 0.f; acc[dt][2] = 0.f; acc[dt][3] = 0.f; }
#pragma unroll
    for (int dt = 0; dt < 4; dt++) {
      const int d = dt * 16 + lo, sw = d & 7;
      const _Float16* vrow = &Vt[d * 256 + 4 * (hi & 1)];
#pragma unroll
      for (int ntp = 0; ntp < 8; ntp++) {
        f16x4 v0 = *(const f16x4*)&vrow[((4 * ntp + (hi >> 1)) ^ sw) << 3];
        f16x4 v1 = *(const f16x4*)&vrow[((4 * ntp + 2 + (hi >> 1)) ^ sw) << 3];
        f16x8 vt8;
#pragma unroll
        for (int r = 0; r < 4; r++) { vt8[r] = v0[r]; vt8[4 + r] = v1[r]; }
        acc[dt] = __builtin_amdgcn_mfma_f32_16x16x32_f16(pa8[ntp], vt8, acc[dt], 0, 0, 0);
      }
    }
#pragma unroll
    for (int dt = 0; dt < 4; dt++)
#pragma unroll
      for (int r = 0; r < 4; r++)
        O[(size_t)(b * NQ + q0 + 4 * hi + r) * C_ + h * HD_ + dt * 16 + lo] = (_Float16)acc[dt][r];
  }
}

// ---------------- host launcher ----------------
extern "C" void kernel_launch(void* const* d_in, const int* in_sizes, int n_in,
                              void* d_out, int out_size, void* d_ws, size_t ws_size,
                              hipStream_t stream) {
  (void)in_sizes; (void)n_in; (void)out_size;
  const float* x    = (const float*)d_in[0];
  const float* ln1g = (const float*)d_in[1];
  const float* ln1b = (const float*)d_in[2];
  DwP pq { (const float*)d_in[3], (const float*)d_in[4], (const float*)d_in[5],
           (const float*)d_in[6], (const float*)d_in[7], (const float*)d_in[8] };
  const float* Wq = (const float*)d_in[9];  const float* bq = (const float*)d_in[10];
  DwP pk { (const float*)d_in[11], (const float*)d_in[12], (const float*)d_in[13],
           (const float*)d_in[14], (const float*)d_in[15], (const float*)d_in[16] };
  const float* Wk = (const float*)d_in[17]; const float* bk = (const float*)d_in[18];
  DwP pv { (const float*)d_in[19], (const float*)d_in[20], (const float*)d_in[21],
           (const float*)d_in[22], (const float*)d_in[23], (const float*)d_in[24] };
  const float* Wv = (const float*)d_in[25]; const float* bv = (const float*)d_in[26];
  const float* ln2g = (const float*)d_in[27];
  const float* ln2b = (const float*)d_in[28];
  const float* W1 = (const float*)d_in[29]; const float* b1 = (const float*)d_in[30];
  const float* W2 = (const float*)d_in[31]; const float* b2 = (const float*)d_in[32];

  char* ws = (char*)d_ws;
  _Float16* gbuf = (_Float16*)(ws + 0);              // 32768*3072*2 = 201326592
  _Float16* xn   = (_Float16*)(ws + 0);              // 48MB
  _Float16* qb   = (_Float16*)(ws + 50331648);       // 48MB
  _Float16* tk   = (_Float16*)(ws + 100663296);      // 12MB
  _Float16* tv   = (_Float16*)(ws + 113246208);      // 12MB (reused as vT)
  _Float16* vTb  = tv;
  _Float16* kb   = (_Float16*)(ws + 125829120);      // 12MB
  _Float16* vbuf = (_Float16*)(ws + 138412032);      // 12MB
  _Float16* o    = (_Float16*)(ws + 150994944);      // 48MB, ends 201326592
  _Float16* tq   = (_Float16*)(ws + 201326592);      // 48MB (reused as hb)
  _Float16* hb   = tq;
  _Float16* wqh  = (_Float16*)(ws + 251658240);
  _Float16* wkh  = (_Float16*)(ws + 252837888);
  _Float16* wvh  = (_Float16*)(ws + 254017536);
  _Float16* w1h  = (_Float16*)(ws + 255197184);
  _Float16* w2h  = (_Float16*)(ws + 259915776);      // ends 264634368 (~252MB)
  // optional f16 residual buffer (48MB) above everything else
  const size_t R16_OFF = 264634368;
  const size_t R16_SZ  = (size_t)NB * NQ * C_ * 2;   // 50331648
  _Float16* r16 = (ws_size >= R16_OFF + R16_SZ) ? (_Float16*)(ws + R16_OFF) : nullptr;
  float* out = (float*)d_out;

  ln_fwd_kernel<<<NB * NQ, 256, 0, stream>>>(x, ln1g, ln1b, xn);
  cast_all_kernel<<<2048, 256, 0, stream>>>(Wq, Wk, Wv, W1, W2, wqh, wkh, wvh, w1h, w2h);
  dw_fused_kernel<<<dim3(16, 4, NB), 384, 0, stream>>>(xn, pq, pk, pv, tq, tk, tv);
  gemm_f16<0><<<1536, 256, 0, stream>>>(tq, wqh, bq, qb, nullptr, nullptr, NB * NQ, C_, C_, 6);
  gemm_kv<<<768, 256, 0, stream>>>(tk, wkh, bk, kb, tv, wvh, bv, vbuf);
  vtrans_kernel<<<dim3(4, 3, NB), 256, 0, stream>>>(vbuf, vTb);
  attn_kernel<<<NB * NH_ * 2, 512, 0, stream>>>(qb, kb, vTb, o);
  resln2_kernel<<<NB * NQ, 256, 0, stream>>>(x, o, ln2g, ln2b, out, r16, hb);
  gemm_f16<1><<<6144, 256, 0, stream>>>(hb, w1h, b1, gbuf, nullptr, nullptr, NB * NQ, FFC, C_, 24);
  gemm_f16<2><<<1536, 256, 0, stream>>>(gbuf, w2h, b2, nullptr, out, r16, NB * NQ, C_, FFC, 6);
}